// Round 2
// baseline (380.948 us; speedup 1.0000x reference)
//
#include <hip/hip_runtime.h>

#define IN_H 512
#define IN_W 512

// One block = 8-row x 256-col strip (32 tiles), all 3 channels.
// Grid: 32 batches * 64 strip-rows * 2 strip-cols = 4096 blocks.
//
// LDS (38.3 KB -> 4 blocks/CU):
//  Ys  @     0 : 32 tiles x 68 f64 (tile-major, pad 4)   = 17408
//  CbS @ 17408 : 32 tiles x 18 f64 (4x4 subsampled +2)   =  4608
//  CrS @ 22016 : 32 tiles x 18 f64                       =  4608
//  Zt  @ 26624 : 32 tiles x 68 f32 (Zt[l][i]=Z[i][l])    =  8704
//  qt  @ 35328 : 3 ch x 8 cols x 9 double2 {1/q, q}      =  3456
//  Dd  @ 38784 : 8x4 f64 half-DCT table                  =   256
//  Dh  @ 39040 : 8x4 f32 half-DCT table                  =   128
// Phases: P0/P1 stage -> [per ch: fused row+col DCT+quant -> barrier ->
// fused row+col IDCT into regs -> barrier] -> RGB convert + store.
// 6 barriers total (was 13).

__global__ __launch_bounds__(256, 4) void jpeg_kernel(
    const float* __restrict__ in, const float* __restrict__ qz,
    const float* __restrict__ dmtx, float* __restrict__ out)
{
    __shared__ __align__(16) unsigned char smem[39168];
    double*  Ys  = (double*) (smem);
    double*  CbS = (double*) (smem + 17408);
    double*  CrS = (double*) (smem + 22016);
    float*   Zt  = (float*)  (smem + 26624);
    double2* qt  = (double2*)(smem + 35328);
    double*  Dd  = (double*) (smem + 38784);
    float*   Dh  = (float*)  (smem + 39040);

    const int t   = threadIdx.x;
    const int blk = blockIdx.x;
    const int b   = blk >> 7;
    const int rr  = blk & 127;
    const int row0 = (rr >> 1) << 3;
    const int col0 = (rr & 1) << 8;
    const int chs = IN_H * IN_W;

    // ---- P0: tables ----
    if (t < 192) {
        const int c = t >> 6, i = (t >> 3) & 7, l = t & 7;
        double v  = (double)qz[t];
        double t1 = rint((rint(v * 255.0) * 50.0 + 50.0) / 100.0); // true div: .5 ties
        double q  = fmin(fmax(t1, 1.0), 255.0);
        qt[(c * 8 + l) * 9 + i] = make_double2(1.0 / q, q);
    }
    if (t < 32) {
        float dv = dmtx[(t >> 2) * 8 + (t & 3)];   // half table D[i][0..3]
        Dd[t] = (double)dv;
        Dh[t] = dv;
    }

    // ---- P1: load, RGB->YCbCr (f64), subsample, stage (tile-major) ----
    const int s  = t >> 6;   // row-pair 0..3
    const int c4 = t & 63;   // 4-col group
    {
        const int base = ((b * 3) * IN_H + row0 + 2 * s) * IN_W + col0 + 4 * c4;
        float4 ra = *(const float4*)(in + base);
        float4 rb = *(const float4*)(in + base + IN_W);
        float4 ga = *(const float4*)(in + base + chs);
        float4 gb = *(const float4*)(in + base + chs + IN_W);
        float4 ba = *(const float4*)(in + base + 2 * chs);
        float4 bb = *(const float4*)(in + base + 2 * chs + IN_W);

        float rA[2][4] = {{ra.x,ra.y,ra.z,ra.w},{rb.x,rb.y,rb.z,rb.w}};
        float gA[2][4] = {{ga.x,ga.y,ga.z,ga.w},{gb.x,gb.y,gb.z,gb.w}};
        float bA[2][4] = {{ba.x,ba.y,ba.z,ba.w},{bb.x,bb.y,bb.z,bb.w}};

        double yv[2][4], cbv[2][4], crv[2][4];
        #pragma unroll
        for (int p = 0; p < 2; ++p) {
            #pragma unroll
            for (int k = 0; k < 4; ++k) {
                double R = 255.0 * (double)rA[p][k];
                double G = 255.0 * (double)gA[p][k];
                double B = 255.0 * (double)bA[p][k];
                double y  =  0.299*R + 0.587*G + 0.114*B;
                double cb = -0.168735892*R - 0.331264108*G + 0.5*B + 128.0;
                double cr =  0.5*R - 0.418687589*G - 0.081312411*B + 128.0;
                yv[p][k]  = fmin(fmax(y , 0.0), 255.0) - 128.0;
                cbv[p][k] = fmin(fmax(cb, 0.0), 255.0);
                crv[p][k] = fmin(fmax(cr, 0.0), 255.0);
            }
        }
        const int tile = c4 >> 1, half = c4 & 1;
        #pragma unroll
        for (int p = 0; p < 2; ++p) {
            double* yp = &Ys[tile * 68 + (2*s + p) * 8 + 4 * half];
            *(double2*)(yp)     = make_double2(yv[p][0], yv[p][1]);
            *(double2*)(yp + 2) = make_double2(yv[p][2], yv[p][3]);
        }
        double m0 = (cbv[0][0]+cbv[0][1]+cbv[1][0]+cbv[1][1])*0.25 - 128.0;
        double m1 = (cbv[0][2]+cbv[0][3]+cbv[1][2]+cbv[1][3])*0.25 - 128.0;
        *(double2*)&CbS[tile * 18 + s * 4 + 2 * half] = make_double2(m0, m1);
        double n0 = (crv[0][0]+crv[0][1]+crv[1][0]+crv[1][1])*0.25 - 128.0;
        double n1 = (crv[0][2]+crv[0][3]+crv[1][2]+crv[1][3])*0.25 - 128.0;
        *(double2*)&CrS[tile * 18 + s * 4 + 2 * half] = make_double2(n0, n1);
    }
    __syncthreads();

    // ---- per-thread constants ----
    const int q8 = t >> 3;     // tile 0..31
    const int l  = t & 7;      // DCT column this thread owns
    double dl0, dl1, dl2, dl3;  // D[l][0..3]
    {
        double2 dA = *(const double2*)&Dd[l * 4];
        double2 dB = *(const double2*)&Dd[l * 4 + 2];
        dl0 = dA.x; dl1 = dA.y; dl2 = dB.x; dl3 = dB.y;
    }
    const double sgn  = (l & 1) ? -1.0 : 1.0;
    const double dl01 = dl0 + dl1, dl23 = dl2 + dl3;
    float dcol[8];                               // D[k][l] via symmetry
    {
        const int   lc = (l < 4) ? l : 7 - l;
        #pragma unroll
        for (int k = 0; k < 8; ++k) {
            float dv = Dh[k * 4 + lc];
            dcol[k] = ((k & 1) && (l >= 4)) ? -dv : dv;
        }
    }

    float acc[3][8];

    #pragma unroll
    for (int c = 0; c < 3; ++c) {
        // ---- fused F: row DCT (stream tile rows) + col DCT + quant -> Zt ----
        double tj[8];
        if (c == 0) {
            const double* base = &Ys[q8 * 68];
            #pragma unroll
            for (int j = 0; j < 8; ++j) {
                const double* p = base + j * 8;
                double2 a0 = *(const double2*)(p);
                double2 a1 = *(const double2*)(p + 2);
                double2 a2 = *(const double2*)(p + 4);
                double2 a3 = *(const double2*)(p + 6);
                double v0 = fma(sgn, a3.y, a0.x);
                double v1 = fma(sgn, a3.x, a0.y);
                double v2 = fma(sgn, a2.y, a1.x);
                double v3 = fma(sgn, a2.x, a1.y);
                tj[j] = dl0*v0 + dl1*v1 + dl2*v2 + dl3*v3;
            }
        } else {
            const double* base = ((c == 1) ? CbS : CrS) + q8 * 18;
            #pragma unroll
            for (int j2 = 0; j2 < 4; ++j2) {
                double2 a0 = *(const double2*)(base + j2 * 4);
                double2 a1 = *(const double2*)(base + j2 * 4 + 2);
                // x = {a,a,b,b,c,c,d,d}; folded with summed coeffs
                double u = dl01 * fma(sgn, a1.y, a0.x) + dl23 * fma(sgn, a1.x, a0.y);
                tj[2*j2] = u; tj[2*j2 + 1] = u;
            }
        }
        double e2[4], o2[4];
        #pragma unroll
        for (int m = 0; m < 4; ++m) { e2[m] = tj[m] + tj[7-m]; o2[m] = tj[m] - tj[7-m]; }

        float zo[8];
        const double2* dd2  = (const double2*)Dd;
        const double2* qrow = &qt[(c * 8 + l) * 9];
        #pragma unroll
        for (int i = 0; i < 8; ++i) {
            double2 dA = dd2[i * 2], dB = dd2[i * 2 + 1];
            double a64 = (i & 1)
                ? dA.x*o2[0] + dA.y*o2[1] + dB.x*o2[2] + dB.y*o2[3]
                : dA.x*e2[0] + dA.y*e2[1] + dB.x*e2[2] + dB.y*e2[3];
            double2 qe = qrow[i];
            zo[i] = (float)(rint(a64 * qe.x) * qe.y);
        }
        float* zp = &Zt[q8 * 68 + l * 8];
        *(float4*)(zp)     = make_float4(zo[0], zo[1], zo[2], zo[3]);
        *(float4*)(zp + 4) = make_float4(zo[4], zo[5], zo[6], zo[7]);
        __syncthreads();

        // ---- fused I: w[j] = sum_k Z[j][k] D[k][l], then column IDCT ----
        float w[8] = {0,0,0,0,0,0,0,0};
        const float* zb = &Zt[q8 * 68];
        #pragma unroll
        for (int k = 0; k < 8; ++k) {
            float4 z0 = *(const float4*)(zb + k * 8);
            float4 z1 = *(const float4*)(zb + k * 8 + 4);
            float dk = dcol[k];
            w[0] += z0.x*dk; w[1] += z0.y*dk; w[2] += z0.z*dk; w[3] += z0.w*dk;
            w[4] += z1.x*dk; w[5] += z1.y*dk; w[6] += z1.z*dk; w[7] += z1.w*dk;
        }
        const float4* dh4 = (const float4*)Dh;
        float se[4] = {0,0,0,0}, so[4] = {0,0,0,0};
        #pragma unroll
        for (int j = 0; j < 8; j += 2) {
            float4 de = dh4[j], dq = dh4[j + 1];
            se[0] += de.x*w[j];   se[1] += de.y*w[j];   se[2] += de.z*w[j];   se[3] += de.w*w[j];
            so[0] += dq.x*w[j+1]; so[1] += dq.y*w[j+1]; so[2] += dq.z*w[j+1]; so[3] += dq.w*w[j+1];
        }
        #pragma unroll
        for (int i2 = 0; i2 < 4; ++i2) {
            acc[c][i2]     = se[i2] + so[i2];
            acc[c][7 - i2] = se[i2] - so[i2];
        }
        if (c < 2) __syncthreads();   // Zt reused by next channel
    }

    // ---- RGB convert + coalesced dword stores (thread t = strip col) ----
    #pragma unroll
    for (int i = 0; i < 8; ++i) {
        float im0 = acc[0][i] + 128.0f;
        float im1 = acc[1][i];
        float im2 = acc[2][i];
        float R  = fminf(fmaxf(im0 + 1.402f*im2, 0.0f), 255.0f);
        float G  = fminf(fmaxf(im0 - 0.344136286f*im1 - 0.714136286f*im2, 0.0f), 255.0f);
        float Bv = fminf(fmaxf(im0 + 1.772f*im1, 0.0f), 255.0f);
        const int base = ((b * 3) * IN_H + row0 + i) * IN_W + col0 + t;
        out[base]           = rintf(R)  * (1.0f/255.0f);
        out[base + chs]     = rintf(G)  * (1.0f/255.0f);
        out[base + 2*chs]   = rintf(Bv) * (1.0f/255.0f);
    }
}

extern "C" void kernel_launch(void* const* d_in, const int* in_sizes, int n_in,
                              void* d_out, int out_size, void* d_ws, size_t ws_size,
                              hipStream_t stream) {
    (void)in_sizes; (void)n_in; (void)out_size; (void)d_ws; (void)ws_size;
    const float* in  = (const float*)d_in[0];
    const float* qz  = (const float*)d_in[1];
    const float* dm  = (const float*)d_in[2];
    float* out = (float*)d_out;
    dim3 grid(4096), blk(256);
    hipLaunchKernelGGL(jpeg_kernel, grid, blk, 0, stream, in, qz, dm, out);
}

// Round 3
// 187.229 us; speedup vs baseline: 2.0347x; 2.0347x over previous
//
#include <hip/hip_runtime.h>

#define IN_H 512
#define IN_W 512

// One block = 8-row x 256-col strip (32 tiles), all 3 channels.
// Grid: 32 batches * 64 strip-rows * 2 strip-cols = 4096 blocks.
//
// LDS (38.3 KB):
//  Ys  @     0 : 32 tiles x 68 f64 (tile-major, pad 4)   = 17408
//  CbS @ 17408 : 32 tiles x 18 f64 (4x4 subsampled +2)   =  4608
//  CrS @ 22016 : 32 tiles x 18 f64                       =  4608
//  Zt  @ 26624 : 32 tiles x 68 f32 (Zt[l][i]=Z[i][l])    =  8704
//  qt  @ 35328 : 3 ch x 8 cols x 9 double2 {1/q, q}      =  3456
//  Dd  @ 38784 : 8x4 f64 half-DCT table                  =   256
//  Dh  @ 39040 : 8x4 f32 half-DCT table                  =   128
//
// R3: launch_bounds (256,2) — R2's (256,4) forced a 64-VGPR allocation and
// ~1 GB of scratch spill traffic (FETCH 377 MB / WRITE 754 MB). Row-DCT now
// streams in fold order (pairs j,7-j -> e2/o2 directly, no tj[8]), chroma
// folds its duplicated rows (4 live doubles), to keep VGPRs ~100.

__global__ __launch_bounds__(256, 2) void jpeg_kernel(
    const float* __restrict__ in, const float* __restrict__ qz,
    const float* __restrict__ dmtx, float* __restrict__ out)
{
    __shared__ __align__(16) unsigned char smem[39168];
    double*  Ys  = (double*) (smem);
    double*  CbS = (double*) (smem + 17408);
    double*  CrS = (double*) (smem + 22016);
    float*   Zt  = (float*)  (smem + 26624);
    double2* qt  = (double2*)(smem + 35328);
    double*  Dd  = (double*) (smem + 38784);
    float*   Dh  = (float*)  (smem + 39040);

    const int t   = threadIdx.x;
    const int blk = blockIdx.x;
    const int b   = blk >> 7;
    const int rr  = blk & 127;
    const int row0 = (rr >> 1) << 3;
    const int col0 = (rr & 1) << 8;
    const int chs = IN_H * IN_W;

    // ---- P0: tables ----
    if (t < 192) {
        const int c = t >> 6, i = (t >> 3) & 7, l = t & 7;
        double v  = (double)qz[t];
        double t1 = rint((rint(v * 255.0) * 50.0 + 50.0) / 100.0); // true div: .5 ties
        double q  = fmin(fmax(t1, 1.0), 255.0);
        qt[(c * 8 + l) * 9 + i] = make_double2(1.0 / q, q);
    }
    if (t < 32) {
        float dv = dmtx[(t >> 2) * 8 + (t & 3)];   // half table D[i][0..3]
        Dd[t] = (double)dv;
        Dh[t] = dv;
    }

    // ---- P1: load, RGB->YCbCr (f64), subsample, stage (tile-major) ----
    const int s  = t >> 6;   // row-pair 0..3
    const int c4 = t & 63;   // 4-col group
    {
        const int base = ((b * 3) * IN_H + row0 + 2 * s) * IN_W + col0 + 4 * c4;
        float4 ra = *(const float4*)(in + base);
        float4 rb = *(const float4*)(in + base + IN_W);
        float4 ga = *(const float4*)(in + base + chs);
        float4 gb = *(const float4*)(in + base + chs + IN_W);
        float4 ba = *(const float4*)(in + base + 2 * chs);
        float4 bb = *(const float4*)(in + base + 2 * chs + IN_W);

        float rA[2][4] = {{ra.x,ra.y,ra.z,ra.w},{rb.x,rb.y,rb.z,rb.w}};
        float gA[2][4] = {{ga.x,ga.y,ga.z,ga.w},{gb.x,gb.y,gb.z,gb.w}};
        float bA[2][4] = {{ba.x,ba.y,ba.z,ba.w},{bb.x,bb.y,bb.z,bb.w}};

        double yv[2][4], cbv[2][4], crv[2][4];
        #pragma unroll
        for (int p = 0; p < 2; ++p) {
            #pragma unroll
            for (int k = 0; k < 4; ++k) {
                double R = 255.0 * (double)rA[p][k];
                double G = 255.0 * (double)gA[p][k];
                double B = 255.0 * (double)bA[p][k];
                double y  =  0.299*R + 0.587*G + 0.114*B;
                double cb = -0.168735892*R - 0.331264108*G + 0.5*B + 128.0;
                double cr =  0.5*R - 0.418687589*G - 0.081312411*B + 128.0;
                yv[p][k]  = fmin(fmax(y , 0.0), 255.0) - 128.0;
                cbv[p][k] = fmin(fmax(cb, 0.0), 255.0);
                crv[p][k] = fmin(fmax(cr, 0.0), 255.0);
            }
        }
        const int tile = c4 >> 1, half = c4 & 1;
        #pragma unroll
        for (int p = 0; p < 2; ++p) {
            double* yp = &Ys[tile * 68 + (2*s + p) * 8 + 4 * half];
            *(double2*)(yp)     = make_double2(yv[p][0], yv[p][1]);
            *(double2*)(yp + 2) = make_double2(yv[p][2], yv[p][3]);
        }
        double m0 = (cbv[0][0]+cbv[0][1]+cbv[1][0]+cbv[1][1])*0.25 - 128.0;
        double m1 = (cbv[0][2]+cbv[0][3]+cbv[1][2]+cbv[1][3])*0.25 - 128.0;
        *(double2*)&CbS[tile * 18 + s * 4 + 2 * half] = make_double2(m0, m1);
        double n0 = (crv[0][0]+crv[0][1]+crv[1][0]+crv[1][1])*0.25 - 128.0;
        double n1 = (crv[0][2]+crv[0][3]+crv[1][2]+crv[1][3])*0.25 - 128.0;
        *(double2*)&CrS[tile * 18 + s * 4 + 2 * half] = make_double2(n0, n1);
    }
    __syncthreads();

    // ---- per-thread constants ----
    const int q8 = t >> 3;     // tile 0..31
    const int l  = t & 7;      // DCT column this thread owns
    double dl0, dl1, dl2, dl3;  // D[l][0..3]
    {
        double2 dA = *(const double2*)&Dd[l * 4];
        double2 dB = *(const double2*)&Dd[l * 4 + 2];
        dl0 = dA.x; dl1 = dA.y; dl2 = dB.x; dl3 = dB.y;
    }
    const double sgn  = (l & 1) ? -1.0 : 1.0;
    const double dl01 = dl0 + dl1, dl23 = dl2 + dl3;
    float dcol[8];                               // D[k][l] via symmetry
    {
        const int   lc = (l < 4) ? l : 7 - l;
        #pragma unroll
        for (int k = 0; k < 8; ++k) {
            float dv = Dh[k * 4 + lc];
            dcol[k] = ((k & 1) && (l >= 4)) ? -dv : dv;
        }
    }

    float acc[3][8];

    #pragma unroll
    for (int c = 0; c < 3; ++c) {
        // ---- fused F: row DCT streamed in fold order -> e2/o2 -> col DCT
        //      + quant -> Zt. No tj[8] intermediate (register diet). ----
        double e2[4], o2[4];
        if (c == 0) {
            const double* base = &Ys[q8 * 68];
            #pragma unroll
            for (int m = 0; m < 4; ++m) {
                double tp[2];
                #pragma unroll
                for (int h = 0; h < 2; ++h) {
                    const double* p = base + (h ? (7 - m) : m) * 8;
                    double2 a0 = *(const double2*)(p);
                    double2 a1 = *(const double2*)(p + 2);
                    double2 a2 = *(const double2*)(p + 4);
                    double2 a3 = *(const double2*)(p + 6);
                    double v0 = fma(sgn, a3.y, a0.x);
                    double v1 = fma(sgn, a3.x, a0.y);
                    double v2 = fma(sgn, a2.y, a1.x);
                    double v3 = fma(sgn, a2.x, a1.y);
                    tp[h] = dl0*v0 + dl1*v1 + dl2*v2 + dl3*v3;
                }
                e2[m] = tp[0] + tp[1];
                o2[m] = tp[0] - tp[1];
            }
        } else {
            const double* base = ((c == 1) ? CbS : CrS) + q8 * 18;
            double u[4];
            #pragma unroll
            for (int j2 = 0; j2 < 4; ++j2) {
                double2 a0 = *(const double2*)(base + j2 * 4);
                double2 a1 = *(const double2*)(base + j2 * 4 + 2);
                // x = {a,a,b,b,c,c,d,d}; folded with summed coeffs
                u[j2] = dl01 * fma(sgn, a1.y, a0.x) + dl23 * fma(sgn, a1.x, a0.y);
            }
            // tj = {u0,u0,u1,u1,u2,u2,u3,u3}  ->  pairwise folds collapse:
            e2[0] = e2[1] = u[0] + u[3];  o2[0] = o2[1] = u[0] - u[3];
            e2[2] = e2[3] = u[1] + u[2];  o2[2] = o2[3] = u[1] - u[2];
        }

        const double2* dd2  = (const double2*)Dd;
        const double2* qrow = &qt[(c * 8 + l) * 9];
        float* zp = &Zt[q8 * 68 + l * 8];
        #pragma unroll
        for (int hh = 0; hh < 2; ++hh) {
            float zo[4];
            #pragma unroll
            for (int ii = 0; ii < 4; ++ii) {
                const int i = hh * 4 + ii;
                double2 dA = dd2[i * 2], dB = dd2[i * 2 + 1];
                double a64 = (i & 1)
                    ? dA.x*o2[0] + dA.y*o2[1] + dB.x*o2[2] + dB.y*o2[3]
                    : dA.x*e2[0] + dA.y*e2[1] + dB.x*e2[2] + dB.y*e2[3];
                double2 qe = qrow[i];
                zo[ii] = (float)(rint(a64 * qe.x) * qe.y);
            }
            *(float4*)(zp + 4 * hh) = make_float4(zo[0], zo[1], zo[2], zo[3]);
        }
        __syncthreads();

        // ---- fused I: w[j] = sum_k Z[j][k] D[k][l], then column IDCT ----
        float w[8] = {0,0,0,0,0,0,0,0};
        const float* zb = &Zt[q8 * 68];
        #pragma unroll
        for (int k = 0; k < 8; ++k) {
            float4 z0 = *(const float4*)(zb + k * 8);
            float4 z1 = *(const float4*)(zb + k * 8 + 4);
            float dk = dcol[k];
            w[0] += z0.x*dk; w[1] += z0.y*dk; w[2] += z0.z*dk; w[3] += z0.w*dk;
            w[4] += z1.x*dk; w[5] += z1.y*dk; w[6] += z1.z*dk; w[7] += z1.w*dk;
        }
        const float4* dh4 = (const float4*)Dh;
        float se[4] = {0,0,0,0}, so[4] = {0,0,0,0};
        #pragma unroll
        for (int j = 0; j < 8; j += 2) {
            float4 de = dh4[j], dq = dh4[j + 1];
            se[0] += de.x*w[j];   se[1] += de.y*w[j];   se[2] += de.z*w[j];   se[3] += de.w*w[j];
            so[0] += dq.x*w[j+1]; so[1] += dq.y*w[j+1]; so[2] += dq.z*w[j+1]; so[3] += dq.w*w[j+1];
        }
        #pragma unroll
        for (int i2 = 0; i2 < 4; ++i2) {
            acc[c][i2]     = se[i2] + so[i2];
            acc[c][7 - i2] = se[i2] - so[i2];
        }
        if (c < 2) __syncthreads();   // Zt reused by next channel
    }

    // ---- RGB convert + coalesced dword stores (thread t = strip col) ----
    #pragma unroll
    for (int i = 0; i < 8; ++i) {
        float im0 = acc[0][i] + 128.0f;
        float im1 = acc[1][i];
        float im2 = acc[2][i];
        float R  = fminf(fmaxf(im0 + 1.402f*im2, 0.0f), 255.0f);
        float G  = fminf(fmaxf(im0 - 0.344136286f*im1 - 0.714136286f*im2, 0.0f), 255.0f);
        float Bv = fminf(fmaxf(im0 + 1.772f*im1, 0.0f), 255.0f);
        const int base = ((b * 3) * IN_H + row0 + i) * IN_W + col0 + t;
        out[base]           = rintf(R)  * (1.0f/255.0f);
        out[base + chs]     = rintf(G)  * (1.0f/255.0f);
        out[base + 2*chs]   = rintf(Bv) * (1.0f/255.0f);
    }
}

extern "C" void kernel_launch(void* const* d_in, const int* in_sizes, int n_in,
                              void* d_out, int out_size, void* d_ws, size_t ws_size,
                              hipStream_t stream) {
    (void)in_sizes; (void)n_in; (void)out_size; (void)d_ws; (void)ws_size;
    const float* in  = (const float*)d_in[0];
    const float* qz  = (const float*)d_in[1];
    const float* dm  = (const float*)d_in[2];
    float* out = (float*)d_out;
    dim3 grid(4096), blk(256);
    hipLaunchKernelGGL(jpeg_kernel, grid, blk, 0, stream, in, qz, dm, out);
}

// Round 4
// 185.057 us; speedup vs baseline: 2.0585x; 1.0117x over previous
//
#include <hip/hip_runtime.h>

#define IN_H 512
#define IN_W 512

// One block = 8-row x 256-col strip (32 tiles), all 3 channels.
// Grid: 32 batches * 64 strip-rows * 2 strip-cols = 4096 blocks.
//
// LDS (38.3 KB -> 4 blocks/CU):
//  Ys  @     0 : 32 tiles x 68 f64 (tile-major, pad 4)   = 17408
//  CbS @ 17408 : 32 tiles x 18 f64 (4x4 subsampled +2)   =  4608
//  CrS @ 22016 : 32 tiles x 18 f64                       =  4608
//  Vt  @ 26624 : 32 tiles x 68 f32 (wave-private patch)  =  8704
//  qt  @ 35328 : 3 ch x 8 cols x 9 double2 {1/q, q}      =  3456
//  Dd  @ 38784 : 8x4 f64 half-DCT table                  =   256
//  Dh  @ 39040 : 8x4 f32 half-DCT table                  =   128
//
// R4: ONE block barrier (after staging). The 8 threads of a tile are 8
// consecutive lanes of one wave, so F->I transpose is wave-synchronous:
// col-IDCT in registers (kills the 48xds_read_b128 Z re-read), then a
// wave-private LDS transpose (8x b32 write + 2x b128 read, <=2-way bank
// aliasing) guarded by wave_barrier only. Thread ends holding pixel ROW x.

__global__ __launch_bounds__(256, 2) void jpeg_kernel(
    const float* __restrict__ in, const float* __restrict__ qz,
    const float* __restrict__ dmtx, float* __restrict__ out)
{
    __shared__ __align__(16) unsigned char smem[39168];
    double*  Ys  = (double*) (smem);
    double*  CbS = (double*) (smem + 17408);
    double*  CrS = (double*) (smem + 22016);
    float*   Vt  = (float*)  (smem + 26624);
    double2* qt  = (double2*)(smem + 35328);
    double*  Dd  = (double*) (smem + 38784);
    float*   Dh  = (float*)  (smem + 39040);

    const int t   = threadIdx.x;
    const int blk = blockIdx.x;
    const int b   = blk >> 7;
    const int rr  = blk & 127;
    const int row0 = (rr >> 1) << 3;
    const int col0 = (rr & 1) << 8;
    const int chs = IN_H * IN_W;

    // ---- P0: tables ----
    if (t < 192) {
        const int c = t >> 6, i = (t >> 3) & 7, l = t & 7;
        double v  = (double)qz[t];
        double t1 = rint((rint(v * 255.0) * 50.0 + 50.0) / 100.0); // true div: .5 ties
        double q  = fmin(fmax(t1, 1.0), 255.0);
        qt[(c * 8 + l) * 9 + i] = make_double2(1.0 / q, q);
    }
    if (t < 32) {
        float dv = dmtx[(t >> 2) * 8 + (t & 3)];   // half table D[i][0..3]
        Dd[t] = (double)dv;
        Dh[t] = dv;
    }

    // ---- P1: load, RGB->YCbCr (f64), subsample, stage (tile-major) ----
    const int s  = t >> 6;   // row-pair 0..3
    const int c4 = t & 63;   // 4-col group
    {
        const int base = ((b * 3) * IN_H + row0 + 2 * s) * IN_W + col0 + 4 * c4;
        float4 ra = *(const float4*)(in + base);
        float4 rb = *(const float4*)(in + base + IN_W);
        float4 ga = *(const float4*)(in + base + chs);
        float4 gb = *(const float4*)(in + base + chs + IN_W);
        float4 ba = *(const float4*)(in + base + 2 * chs);
        float4 bb = *(const float4*)(in + base + 2 * chs + IN_W);

        float rA[2][4] = {{ra.x,ra.y,ra.z,ra.w},{rb.x,rb.y,rb.z,rb.w}};
        float gA[2][4] = {{ga.x,ga.y,ga.z,ga.w},{gb.x,gb.y,gb.z,gb.w}};
        float bA[2][4] = {{ba.x,ba.y,ba.z,ba.w},{bb.x,bb.y,bb.z,bb.w}};

        double yv[2][4], cbv[2][4], crv[2][4];
        #pragma unroll
        for (int p = 0; p < 2; ++p) {
            #pragma unroll
            for (int k = 0; k < 4; ++k) {
                double R = 255.0 * (double)rA[p][k];
                double G = 255.0 * (double)gA[p][k];
                double B = 255.0 * (double)bA[p][k];
                double y  =  0.299*R + 0.587*G + 0.114*B;
                double cb = -0.168735892*R - 0.331264108*G + 0.5*B + 128.0;
                double cr =  0.5*R - 0.418687589*G - 0.081312411*B + 128.0;
                yv[p][k]  = fmin(fmax(y , 0.0), 255.0) - 128.0;
                cbv[p][k] = fmin(fmax(cb, 0.0), 255.0);
                crv[p][k] = fmin(fmax(cr, 0.0), 255.0);
            }
        }
        const int tile = c4 >> 1, half = c4 & 1;
        #pragma unroll
        for (int p = 0; p < 2; ++p) {
            double* yp = &Ys[tile * 68 + (2*s + p) * 8 + 4 * half];
            *(double2*)(yp)     = make_double2(yv[p][0], yv[p][1]);
            *(double2*)(yp + 2) = make_double2(yv[p][2], yv[p][3]);
        }
        double m0 = (cbv[0][0]+cbv[0][1]+cbv[1][0]+cbv[1][1])*0.25 - 128.0;
        double m1 = (cbv[0][2]+cbv[0][3]+cbv[1][2]+cbv[1][3])*0.25 - 128.0;
        *(double2*)&CbS[tile * 18 + s * 4 + 2 * half] = make_double2(m0, m1);
        double n0 = (crv[0][0]+crv[0][1]+crv[1][0]+crv[1][1])*0.25 - 128.0;
        double n1 = (crv[0][2]+crv[0][3]+crv[1][2]+crv[1][3])*0.25 - 128.0;
        *(double2*)&CrS[tile * 18 + s * 4 + 2 * half] = make_double2(n0, n1);
    }
    __syncthreads();   // the ONLY block barrier

    // ---- per-thread constants ----
    const int q8 = t >> 3;     // tile 0..31
    const int l  = t & 7;      // DCT column (F) / pixel row (I) this thread owns
    double dl0, dl1, dl2, dl3;  // D[l][0..3]
    {
        double2 dA = *(const double2*)&Dd[l * 4];
        double2 dB = *(const double2*)&Dd[l * 4 + 2];
        dl0 = dA.x; dl1 = dA.y; dl2 = dB.x; dl3 = dB.y;
    }
    const double sgn  = (l & 1) ? -1.0 : 1.0;
    const double dl01 = dl0 + dl1, dl23 = dl2 + dl3;
    // f32 half-table in registers (reused by both IDCT folds, all channels)
    const float4* dh4p = (const float4*)Dh;
    float4 d0 = dh4p[0], d1 = dh4p[1], d2 = dh4p[2], d3 = dh4p[3];
    float4 d4 = dh4p[4], d5 = dh4p[5], d6 = dh4p[6], d7 = dh4p[7];

    float acc[3][8];
    float* vtw = &Vt[q8 * 68];          // wave-private tile patch

    #pragma unroll
    for (int c = 0; c < 3; ++c) {
        // ---- F: row DCT streamed in fold order -> e2/o2 -> col DCT + quant ----
        double e2[4], o2[4];
        if (c == 0) {
            const double* base = &Ys[q8 * 68];
            #pragma unroll
            for (int m = 0; m < 4; ++m) {
                double tp[2];
                #pragma unroll
                for (int h = 0; h < 2; ++h) {
                    const double* p = base + (h ? (7 - m) : m) * 8;
                    double2 a0 = *(const double2*)(p);
                    double2 a1 = *(const double2*)(p + 2);
                    double2 a2 = *(const double2*)(p + 4);
                    double2 a3 = *(const double2*)(p + 6);
                    double v0 = fma(sgn, a3.y, a0.x);
                    double v1 = fma(sgn, a3.x, a0.y);
                    double v2 = fma(sgn, a2.y, a1.x);
                    double v3 = fma(sgn, a2.x, a1.y);
                    tp[h] = dl0*v0 + dl1*v1 + dl2*v2 + dl3*v3;
                }
                e2[m] = tp[0] + tp[1];
                o2[m] = tp[0] - tp[1];
            }
        } else {
            const double* base = ((c == 1) ? CbS : CrS) + q8 * 18;
            double u4[4];
            #pragma unroll
            for (int j2 = 0; j2 < 4; ++j2) {
                double2 a0 = *(const double2*)(base + j2 * 4);
                double2 a1 = *(const double2*)(base + j2 * 4 + 2);
                u4[j2] = dl01 * fma(sgn, a1.y, a0.x) + dl23 * fma(sgn, a1.x, a0.y);
            }
            e2[0] = e2[1] = u4[0] + u4[3];  o2[0] = o2[1] = u4[0] - u4[3];
            e2[2] = e2[3] = u4[1] + u4[2];  o2[2] = o2[3] = u4[1] - u4[2];
        }

        // zo[i] = Z[i][l] (exact small integers in f32)
        float zo[8];
        {
            const double2* dd2  = (const double2*)Dd;
            const double2* qrow = &qt[(c * 8 + l) * 9];
            #pragma unroll
            for (int i = 0; i < 8; ++i) {
                double2 dA = dd2[i * 2], dB = dd2[i * 2 + 1];
                double a64 = (i & 1)
                    ? dA.x*o2[0] + dA.y*o2[1] + dB.x*o2[2] + dB.y*o2[3]
                    : dA.x*e2[0] + dA.y*e2[1] + dB.x*e2[2] + dB.y*e2[3];
                double2 qe = qrow[i];
                zo[i] = (float)(rint(a64 * qe.x) * qe.y);
            }
        }

        // ---- col IDCT in registers: u[x] = sum_i zo[i] * D[i][x] ----
        float u[8];
        {
            float se0 = zo[0]*d0.x + zo[2]*d2.x + zo[4]*d4.x + zo[6]*d6.x;
            float se1 = zo[0]*d0.y + zo[2]*d2.y + zo[4]*d4.y + zo[6]*d6.y;
            float se2 = zo[0]*d0.z + zo[2]*d2.z + zo[4]*d4.z + zo[6]*d6.z;
            float se3 = zo[0]*d0.w + zo[2]*d2.w + zo[4]*d4.w + zo[6]*d6.w;
            float so0 = zo[1]*d1.x + zo[3]*d3.x + zo[5]*d5.x + zo[7]*d7.x;
            float so1 = zo[1]*d1.y + zo[3]*d3.y + zo[5]*d5.y + zo[7]*d7.y;
            float so2 = zo[1]*d1.z + zo[3]*d3.z + zo[5]*d5.z + zo[7]*d7.z;
            float so3 = zo[1]*d1.w + zo[3]*d3.w + zo[5]*d5.w + zo[7]*d7.w;
            u[0]=se0+so0; u[7]=se0-so0;
            u[1]=se1+so1; u[6]=se1-so1;
            u[2]=se2+so2; u[5]=se2-so2;
            u[3]=se3+so3; u[4]=se3-so3;
        }

        // ---- wave-local transpose: Vt[tile][x][l] = u[x] ----
        #pragma unroll
        for (int x = 0; x < 8; ++x) vtw[x * 8 + l] = u[x];
        __builtin_amdgcn_wave_barrier();   // DS ops of a wave execute in order
        float w2[8];
        {
            const float* vr = vtw + l * 8;   // this thread now owns pixel row x=l
            float4 wa = *(const float4*)(vr);
            float4 wb = *(const float4*)(vr + 4);
            w2[0]=wa.x; w2[1]=wa.y; w2[2]=wa.z; w2[3]=wa.w;
            w2[4]=wb.x; w2[5]=wb.y; w2[6]=wb.z; w2[7]=wb.w;
        }
        __builtin_amdgcn_wave_barrier();   // next channel overwrites Vt

        // ---- row IDCT: pix[x][y] = sum_k w2[k] * D[k][y] ----
        {
            float re0 = w2[0]*d0.x + w2[2]*d2.x + w2[4]*d4.x + w2[6]*d6.x;
            float re1 = w2[0]*d0.y + w2[2]*d2.y + w2[4]*d4.y + w2[6]*d6.y;
            float re2 = w2[0]*d0.z + w2[2]*d2.z + w2[4]*d4.z + w2[6]*d6.z;
            float re3 = w2[0]*d0.w + w2[2]*d2.w + w2[4]*d4.w + w2[6]*d6.w;
            float ro0 = w2[1]*d1.x + w2[3]*d3.x + w2[5]*d5.x + w2[7]*d7.x;
            float ro1 = w2[1]*d1.y + w2[3]*d3.y + w2[5]*d5.y + w2[7]*d7.y;
            float ro2 = w2[1]*d1.z + w2[3]*d3.z + w2[5]*d5.z + w2[7]*d7.z;
            float ro3 = w2[1]*d1.w + w2[3]*d3.w + w2[5]*d5.w + w2[7]*d7.w;
            acc[c][0]=re0+ro0; acc[c][7]=re0-ro0;
            acc[c][1]=re1+ro1; acc[c][6]=re1-ro1;
            acc[c][2]=re2+ro2; acc[c][5]=re2-ro2;
            acc[c][3]=re3+ro3; acc[c][4]=re3-ro3;
        }
    }

    // ---- RGB convert + row-major float4 stores (thread = pixel row l) ----
    {
        const int obase = ((b * 3) * IN_H + row0 + l) * IN_W + col0 + q8 * 8;
        float R4[8], G4[8], B4[8];
        #pragma unroll
        for (int y = 0; y < 8; ++y) {
            float im0 = acc[0][y] + 128.0f;
            float im1 = acc[1][y];
            float im2 = acc[2][y];
            float R  = fminf(fmaxf(im0 + 1.402f*im2, 0.0f), 255.0f);
            float G  = fminf(fmaxf(im0 - 0.344136286f*im1 - 0.714136286f*im2, 0.0f), 255.0f);
            float Bv = fminf(fmaxf(im0 + 1.772f*im1, 0.0f), 255.0f);
            R4[y] = rintf(R)  * (1.0f/255.0f);
            G4[y] = rintf(G)  * (1.0f/255.0f);
            B4[y] = rintf(Bv) * (1.0f/255.0f);
        }
        *(float4*)(out + obase)               = make_float4(R4[0],R4[1],R4[2],R4[3]);
        *(float4*)(out + obase + 4)           = make_float4(R4[4],R4[5],R4[6],R4[7]);
        *(float4*)(out + obase + chs)         = make_float4(G4[0],G4[1],G4[2],G4[3]);
        *(float4*)(out + obase + chs + 4)     = make_float4(G4[4],G4[5],G4[6],G4[7]);
        *(float4*)(out + obase + 2*chs)       = make_float4(B4[0],B4[1],B4[2],B4[3]);
        *(float4*)(out + obase + 2*chs + 4)   = make_float4(B4[4],B4[5],B4[6],B4[7]);
    }
}

extern "C" void kernel_launch(void* const* d_in, const int* in_sizes, int n_in,
                              void* d_out, int out_size, void* d_ws, size_t ws_size,
                              hipStream_t stream) {
    (void)in_sizes; (void)n_in; (void)out_size; (void)d_ws; (void)ws_size;
    const float* in  = (const float*)d_in[0];
    const float* qz  = (const float*)d_in[1];
    const float* dm  = (const float*)d_in[2];
    float* out = (float*)d_out;
    dim3 grid(4096), blk(256);
    hipLaunchKernelGGL(jpeg_kernel, grid, blk, 0, stream, in, qz, dm, out);
}